// Round 11
// baseline (961.747 us; speedup 1.0000x reference)
//
#include <hip/hip_runtime.h>
#include <hip/hip_bf16.h>
#include <math.h>

// METG forward. Round 11: flash reverted to QB=64 (VALU-bound; QB=128 null+lost
// parallelism). NEW gemm_ln: out-proj+LN1 and ff2+LN2 fused (M64xN512 tile,
// LN epilogue in-block) -- kills 6 LN dispatches + resb stream.
// Shapes: B=32 S=512 F_IN=64 D=512 DFF=2048 MEM=1024 L=3 H=8 DH=64

namespace {

typedef unsigned short ushort_t;
using bf16x8 = __attribute__((ext_vector_type(8))) __bf16;
using f32x4 = __attribute__((ext_vector_type(4))) float;
using ushort8 = __attribute__((ext_vector_type(8))) unsigned short;

constexpr int Mrows = 32 * 512;  // 16384
constexpr size_t MB = 1048576;

__device__ __forceinline__ unsigned short f2bf(float f) {
  unsigned int u = __builtin_bit_cast(unsigned int, f);
  u += 0x7fffu + ((u >> 16) & 1u);
  return (unsigned short)(u >> 16);
}
__device__ __forceinline__ float bf2f(ushort_t u) {
  unsigned int v = ((unsigned int)u) << 16;
  return __builtin_bit_cast(float, v);
}

__device__ __forceinline__ void g2lds16(const void* g, void* l) {
  __builtin_amdgcn_global_load_lds(
      (const __attribute__((address_space(1))) unsigned int*)g,
      (__attribute__((address_space(3))) unsigned int*)l, 16, 0, 0);
}

// ---------------- gemm256 (round-8): 256x256 tile, 8 waves, dbuf LDS,
// counted vmcnt(8) + raw s_barrier (no drain in K-loop).
template <bool RELU, bool BF16OUT>
__global__ __launch_bounds__(512, 2) void gemm256(const ushort_t* __restrict__ A,
                                                  const ushort_t* __restrict__ B,
                                                  const float* __restrict__ bias,
                                                  void* __restrict__ Cv,
                                                  int K, int lda, int ldc) {
  __shared__ __align__(16) ushort_t As[2][256 * 64];
  __shared__ __align__(16) ushort_t Bs[2][256 * 64];
  const int t = threadIdx.x;
  const int w = t >> 6, l = t & 63;
  const int m0 = blockIdx.x << 8, n0 = blockIdx.y << 8;
  const int srow8 = l >> 3;
  const int scol = ((l & 7) ^ srow8) << 3;
  const ushort_t* agp = A + (size_t)(m0 + w * 32 + srow8) * lda + scol;
  const ushort_t* bgp = B + (size_t)(n0 + w * 32 + srow8) * K + scol;
  const int wr = w >> 2, wcn = w & 3;
  const int lr = l & 15, g = l >> 4;
  const int sw = (l & 7) << 4;
  const int nt = K >> 6;
  f32x4 acc[8][4] = {};
#pragma unroll
  for (int i = 0; i < 4; ++i) {
    g2lds16(agp + (size_t)(i * 8) * lda, &As[0][(w * 32 + i * 8) * 64]);
    g2lds16(bgp + (size_t)(i * 8) * K, &Bs[0][(w * 32 + i * 8) * 64]);
  }
#pragma unroll
  for (int i = 0; i < 4; ++i) {
    g2lds16(agp + (size_t)(i * 8) * lda + 64, &As[1][(w * 32 + i * 8) * 64]);
    g2lds16(bgp + (size_t)(i * 8) * K + 64, &Bs[1][(w * 32 + i * 8) * 64]);
  }
  for (int j = 0; j < nt; ++j) {
    const int c = j & 1;
    asm volatile("s_waitcnt vmcnt(8)" ::: "memory");
    __builtin_amdgcn_s_barrier();
    asm volatile("" ::: "memory");
    const char* abase = (const char*)&As[c][0];
    const char* bbase = (const char*)&Bs[c][0];
#pragma unroll
    for (int ki = 0; ki < 2; ++ki) {
      const int kb = (ki * 64 + g * 16) ^ sw;
      bf16x8 af[8], bfr[4];
#pragma unroll
      for (int mi = 0; mi < 8; ++mi)
        af[mi] = *(const bf16x8*)(abase + (wr * 128 + mi * 16 + lr) * 128 + kb);
#pragma unroll
      for (int ni = 0; ni < 4; ++ni)
        bfr[ni] = *(const bf16x8*)(bbase + (wcn * 64 + ni * 16 + lr) * 128 + kb);
      __builtin_amdgcn_s_setprio(1);
#pragma unroll
      for (int mi = 0; mi < 8; ++mi)
#pragma unroll
        for (int ni = 0; ni < 4; ++ni)
          acc[mi][ni] = __builtin_amdgcn_mfma_f32_16x16x32_bf16(af[mi], bfr[ni],
                                                                acc[mi][ni], 0, 0, 0);
      __builtin_amdgcn_s_setprio(0);
    }
    asm volatile("s_waitcnt lgkmcnt(0)" ::: "memory");
    __builtin_amdgcn_s_barrier();
    asm volatile("" ::: "memory");
    if (j + 2 < nt) {
      const size_t ko = (size_t)(j + 2) * 64;
#pragma unroll
      for (int i = 0; i < 4; ++i) {
        g2lds16(agp + (size_t)(i * 8) * lda + ko, &As[c][(w * 32 + i * 8) * 64]);
        g2lds16(bgp + (size_t)(i * 8) * K + ko, &Bs[c][(w * 32 + i * 8) * 64]);
      }
    }
  }
  float bb[4];
#pragma unroll
  for (int ni = 0; ni < 4; ++ni) {
    const int ci = n0 + wcn * 64 + ni * 16 + lr;
    bb[ni] = bias ? bias[ci] : 0.f;
  }
  const int crow0 = m0 + wr * 128 + g * 4;
#pragma unroll
  for (int mi = 0; mi < 8; ++mi)
#pragma unroll
    for (int ni = 0; ni < 4; ++ni) {
      const int ci = n0 + wcn * 64 + ni * 16 + lr;
#pragma unroll
      for (int v = 0; v < 4; ++v) {
        float val = acc[mi][ni][v] + bb[ni];
        if (RELU) val = fmaxf(val, 0.f);
        const size_t off = (size_t)(crow0 + mi * 16 + v) * ldc + ci;
        if (BF16OUT) ((ushort_t*)Cv)[off] = f2bf(val);
        else         ((float*)Cv)[off] = val;
      }
    }
}

// ---------------- gemm_ln: out = LN(res + A@B^T + bias) -> bf16 (stride ldo)
// M-tile 64, N=512 full row. 512 thr = 8 waves (2M x 4N), acc[2][8].
// LDS: A 8KB | B 64KB; epilogue reuses as y[64][520] bf16.
__global__ __launch_bounds__(512, 2) void gemm_ln(const ushort_t* __restrict__ A,
                                                  const ushort_t* __restrict__ B,
                                                  const float* __restrict__ bias,
                                                  const ushort_t* __restrict__ res,
                                                  const float* __restrict__ gg,
                                                  const float* __restrict__ bt,
                                                  ushort_t* __restrict__ out,
                                                  int K, int lda, int ldo) {
  __shared__ __align__(16) char smem[8192 + 65536];
  ushort_t* As = (ushort_t*)smem;             // [64][64]
  ushort_t* Bs = (ushort_t*)(smem + 8192);    // [512][64]
  const int t = threadIdx.x;
  const int w = t >> 6, l = t & 63;
  const int m0 = blockIdx.x << 6;
  const int r8 = l >> 3;
  const int scol = ((l & 7) ^ r8) << 3;
  const ushort_t* agp = A + (size_t)(m0 + w * 8 + r8) * lda + scol;
  const ushort_t* bgp = B + (size_t)(w * 64 + r8) * K + scol;
  const int wr = w & 1, wcn = w >> 1;   // 2 M-halves x 4 N-quarters
  const int lr = l & 15, gq = l >> 4;
  const int sw = (l & 7) << 4;
  f32x4 acc[2][8] = {};
  for (int kt = 0; kt < K; kt += 64) {
    __syncthreads();
    g2lds16(agp + kt, As + (w * 8) * 64);
#pragma unroll
    for (int i = 0; i < 8; ++i)
      g2lds16(bgp + (size_t)(i * 8) * K + kt, Bs + (w * 64 + i * 8) * 64);
    __syncthreads();
#pragma unroll
    for (int ki = 0; ki < 2; ++ki) {
      const int kb = (ki * 64 + gq * 16) ^ sw;
      bf16x8 af[2], bfr[8];
#pragma unroll
      for (int mi = 0; mi < 2; ++mi)
        af[mi] = *(const bf16x8*)((const char*)As + (wr * 32 + mi * 16 + lr) * 128 + kb);
#pragma unroll
      for (int ni = 0; ni < 8; ++ni)
        bfr[ni] = *(const bf16x8*)((const char*)Bs + (wcn * 128 + ni * 16 + lr) * 128 + kb);
#pragma unroll
      for (int mi = 0; mi < 2; ++mi)
#pragma unroll
        for (int ni = 0; ni < 8; ++ni)
          acc[mi][ni] = __builtin_amdgcn_mfma_f32_16x16x32_bf16(af[mi], bfr[ni],
                                                                acc[mi][ni], 0, 0, 0);
    }
  }
  float bb[8];
#pragma unroll
  for (int ni = 0; ni < 8; ++ni) bb[ni] = bias[wcn * 128 + ni * 16 + lr];
  __syncthreads();  // LDS reads done; reuse as y
  {
    char* Ys = smem;  // bf16 [64][520]  (row stride 1040B, 16B-aligned)
#pragma unroll
    for (int mi = 0; mi < 2; ++mi)
#pragma unroll
      for (int ni = 0; ni < 8; ++ni) {
        const int col = wcn * 128 + ni * 16 + lr;
#pragma unroll
        for (int v = 0; v < 4; ++v) {
          const int row = wr * 32 + mi * 16 + gq * 4 + v;
          *(ushort_t*)(Ys + row * 1040 + col * 2) = f2bf(acc[mi][ni][v] + bb[ni]);
        }
      }
  }
  __syncthreads();
  {
    const int r = t >> 3, q = t & 7;
    const char* Ys = smem;
    float xs[64];
    float sum = 0.f;
    const ushort_t* rp = res + (size_t)(m0 + r) * 512 + q * 64;
#pragma unroll
    for (int j = 0; j < 8; ++j) {
      ushort8 yv = *(const ushort8*)(Ys + r * 1040 + q * 128 + 16 * j);
      ushort8 rv = *(const ushort8*)(rp + 8 * j);
#pragma unroll
      for (int e = 0; e < 8; ++e) {
        float xv = bf2f(yv[e]) + bf2f(rv[e]);
        xs[8 * j + e] = xv;
        sum += xv;
      }
    }
    sum += __shfl_xor(sum, 1); sum += __shfl_xor(sum, 2); sum += __shfl_xor(sum, 4);
    const float mean = sum * (1.f / 512.f);
    float vs = 0.f;
#pragma unroll
    for (int i = 0; i < 64; ++i) { xs[i] -= mean; vs += xs[i] * xs[i]; }
    vs += __shfl_xor(vs, 1); vs += __shfl_xor(vs, 2); vs += __shfl_xor(vs, 4);
    const float rstd = rsqrtf(vs * (1.f / 512.f) + 1e-5f);
    ushort_t* op = out + (size_t)(m0 + r) * ldo + q * 64;
#pragma unroll
    for (int j = 0; j < 8; ++j) {
      float4 g0 = *(const float4*)(gg + q * 64 + 8 * j);
      float4 g1 = *(const float4*)(gg + q * 64 + 8 * j + 4);
      float4 b0 = *(const float4*)(bt + q * 64 + 8 * j);
      float4 b1 = *(const float4*)(bt + q * 64 + 8 * j + 4);
      ushort8 o;
      o[0] = f2bf(xs[8 * j + 0] * rstd * g0.x + b0.x);
      o[1] = f2bf(xs[8 * j + 1] * rstd * g0.y + b0.y);
      o[2] = f2bf(xs[8 * j + 2] * rstd * g0.z + b0.z);
      o[3] = f2bf(xs[8 * j + 3] * rstd * g0.w + b0.w);
      o[4] = f2bf(xs[8 * j + 4] * rstd * g1.x + b1.x);
      o[5] = f2bf(xs[8 * j + 5] * rstd * g1.y + b1.y);
      o[6] = f2bf(xs[8 * j + 6] * rstd * g1.z + b1.z);
      o[7] = f2bf(xs[8 * j + 7] * rstd * g1.w + b1.w);
      *(ushort8*)(op + 8 * j) = o;
    }
  }
}

// ---------------- bf16 MFMA GEMM 128x128 (round-4 proven structure)
template <bool RELU, bool BF16OUT>
__global__ __launch_bounds__(256) void gemm_bf16(const ushort_t* __restrict__ A,
                                                 const ushort_t* __restrict__ B,
                                                 const float* __restrict__ bias,
                                                 void* __restrict__ Cv,
                                                 int K, int lda, int ldc, int Nclip) {
  __shared__ __align__(16) ushort_t As[128 * 64];
  __shared__ __align__(16) ushort_t Bs[128 * 64];
  const int t = threadIdx.x;
  const int w = t >> 6, l = t & 63;
  const int m0 = blockIdx.x << 7, n0 = blockIdx.y << 7;
  const int srow8 = l >> 3;
  const int scol = ((l & 7) ^ srow8) << 3;
  const ushort_t* agp = A + (size_t)(m0 + w * 32 + srow8) * lda + scol;
  const ushort_t* bgp = B + (size_t)(n0 + w * 32 + srow8) * K + scol;
  ushort_t* alds = &As[(w * 32) * 64];
  ushort_t* blds = &Bs[(w * 32) * 64];
  const int wr = w >> 1, wc = w & 1;
  const int lr = l & 15, g = l >> 4;
  const int sw = (l & 7) << 4;
  f32x4 acc[4][4] = {};
  for (int kt = 0; kt < K; kt += 64) {
    __syncthreads();
#pragma unroll
    for (int i = 0; i < 4; ++i) {
      g2lds16(agp + (size_t)(i * 8) * lda + kt, alds + i * 8 * 64);
      g2lds16(bgp + (size_t)(i * 8) * K + kt, blds + i * 8 * 64);
    }
    __syncthreads();
#pragma unroll
    for (int ki = 0; ki < 2; ++ki) {
      bf16x8 af[4], bf[4];
      const int kb = (ki * 64 + g * 16) ^ sw;
#pragma unroll
      for (int mi = 0; mi < 4; ++mi)
        af[mi] = *(const bf16x8*)((const char*)As + (wr * 64 + mi * 16 + lr) * 128 + kb);
#pragma unroll
      for (int ni = 0; ni < 4; ++ni)
        bf[ni] = *(const bf16x8*)((const char*)Bs + (wc * 64 + ni * 16 + lr) * 128 + kb);
#pragma unroll
      for (int mi = 0; mi < 4; ++mi)
#pragma unroll
        for (int ni = 0; ni < 4; ++ni)
          acc[mi][ni] = __builtin_amdgcn_mfma_f32_16x16x32_bf16(af[mi], bf[ni],
                                                                acc[mi][ni], 0, 0, 0);
    }
  }
  float bb[4];
#pragma unroll
  for (int ni = 0; ni < 4; ++ni) {
    const int ci = n0 + wc * 64 + ni * 16 + lr;
    bb[ni] = (bias && ci < Nclip) ? bias[ci] : 0.f;
  }
  const int crow0 = m0 + wr * 64 + g * 4;
#pragma unroll
  for (int mi = 0; mi < 4; ++mi)
#pragma unroll
    for (int ni = 0; ni < 4; ++ni) {
      const int ci = n0 + wc * 64 + ni * 16 + lr;
      if (ci >= Nclip) continue;
#pragma unroll
      for (int v = 0; v < 4; ++v) {
        float val = acc[mi][ni][v] + bb[ni];
        if (RELU) val = fmaxf(val, 0.f);
        const size_t off = (size_t)(crow0 + mi * 16 + v) * ldc + ci;
        if (BF16OUT) ((ushort_t*)Cv)[off] = f2bf(val);
        else         ((float*)Cv)[off] = val;
      }
    }
}

// ---------------- bf16 MFMA flash attention (round-9: QB=64, grid (h,qb,b))
__global__ __launch_bounds__(256) void flash_attn_mfma(const ushort_t* __restrict__ qkvb,
                                                       ushort_t* __restrict__ ctxb) {
  __shared__ __align__(16) ushort_t Qs[64 * 64];
  __shared__ __align__(16) ushort_t Ks[64 * 64];
  __shared__ __align__(16) ushort_t VT[64 * 64];
  __shared__ __align__(16) ushort_t Ps[64 * 64];
  const int hh = blockIdx.x, qb = blockIdx.y, b = blockIdx.z;
  const int t = threadIdx.x, w = t >> 6, l = t & 63;
  const int g = l >> 4, lr = l & 15, l7 = l & 7;
  const ushort_t* qkv0 = qkvb + (size_t)b * 512 * 1536 + hh * 64;
  {
    const int r8 = l >> 3;
    const int gcol = (l7 ^ r8) << 3;
#pragma unroll
    for (int i = 0; i < 2; ++i) {
      const int row = w * 16 + i * 8 + r8;
      g2lds16(qkv0 + (size_t)(qb * 64 + row) * 1536 + gcol, &Qs[(w * 16 + i * 8) * 64]);
    }
  }
  float mst = -INFINITY, lst = 0.f;
  f32x4 oacc[4] = {};
  const int vk0 = (t & 31) * 2;
  const int vdh0 = (t >> 5) * 8;
  for (int kt = 0; kt < 8; ++kt) {
    __syncthreads();
    {
      const int r8 = l >> 3;
      const int gcol = (l7 ^ r8) << 3;
#pragma unroll
      for (int i = 0; i < 2; ++i) {
        const int row = w * 16 + i * 8 + r8;
        g2lds16(qkv0 + 512 + (size_t)(kt * 64 + row) * 1536 + gcol,
                &Ks[(w * 16 + i * 8) * 64]);
      }
    }
    {
      const ushort_t* vp = qkv0 + 1024 + (size_t)(kt * 64 + vk0) * 1536 + vdh0;
      ushort8 v0 = *(const ushort8*)vp;
      ushort8 v1 = *(const ushort8*)(vp + 1536);
      const int slotbase = vk0 >> 3;
      const int inb = (vk0 & 7) * 2;
#pragma unroll
      for (int e = 0; e < 8; ++e) {
        const int dh = vdh0 + e;
        unsigned int word = (unsigned int)v0[e] | ((unsigned int)v1[e] << 16);
        *(unsigned int*)((char*)VT + dh * 128 + (((slotbase ^ (dh & 7)) << 4) + inb)) = word;
      }
    }
    __syncthreads();
    f32x4 sacc[4] = {};
#pragma unroll
    for (int ki = 0; ki < 2; ++ki) {
      const int sb = ((ki * 4 + g) ^ l7) << 4;
      bf16x8 qf = *(const bf16x8*)((const char*)Qs + (w * 16 + lr) * 128 + sb);
#pragma unroll
      for (int mi = 0; mi < 4; ++mi) {
        bf16x8 kf = *(const bf16x8*)((const char*)Ks + (mi * 16 + lr) * 128 + sb);
        sacc[mi] = __builtin_amdgcn_mfma_f32_16x16x32_bf16(kf, qf, sacc[mi], 0, 0, 0);
      }
    }
    float p[4][4];
    float cmax = -INFINITY;
#pragma unroll
    for (int mi = 0; mi < 4; ++mi)
#pragma unroll
      for (int v = 0; v < 4; ++v) {
        p[mi][v] = sacc[mi][v] * 0.125f;
        cmax = fmaxf(cmax, p[mi][v]);
      }
    cmax = fmaxf(cmax, __shfl_xor(cmax, 16));
    cmax = fmaxf(cmax, __shfl_xor(cmax, 32));
    const float mnew = fmaxf(mst, cmax);
    const float al = __expf(mst - mnew);
    float csum = 0.f;
#pragma unroll
    for (int mi = 0; mi < 4; ++mi)
#pragma unroll
      for (int v = 0; v < 4; ++v) {
        p[mi][v] = __expf(p[mi][v] - mnew);
        csum += p[mi][v];
      }
    csum += __shfl_xor(csum, 16);
    csum += __shfl_xor(csum, 32);
    lst = lst * al + csum;
    mst = mnew;
#pragma unroll
    for (int mi = 0; mi < 4; ++mi) oacc[mi] *= al;
    {
      char* pbase = (char*)Ps + (w * 16 + lr) * 128;
#pragma unroll
      for (int mi = 0; mi < 4; ++mi)
#pragma unroll
        for (int vp2 = 0; vp2 < 2; ++vp2) {
          const int klo = mi * 16 + g * 4 + vp2 * 2;
          unsigned int word = (unsigned int)f2bf(p[mi][vp2 * 2]) |
                              ((unsigned int)f2bf(p[mi][vp2 * 2 + 1]) << 16);
          *(unsigned int*)(pbase + (((klo >> 3) ^ l7) << 4) + (klo & 7) * 2) = word;
        }
    }
#pragma unroll
    for (int ki = 0; ki < 2; ++ki) {
      const int sb = ((ki * 4 + g) ^ l7) << 4;
      bf16x8 pf = *(const bf16x8*)((const char*)Ps + (w * 16 + lr) * 128 + sb);
#pragma unroll
      for (int mi = 0; mi < 4; ++mi) {
        bf16x8 vf = *(const bf16x8*)((const char*)VT + (mi * 16 + lr) * 128 + sb);
        oacc[mi] = __builtin_amdgcn_mfma_f32_16x16x32_bf16(vf, pf, oacc[mi], 0, 0, 0);
      }
    }
  }
  const float inv = 1.f / lst;
  ushort_t* op = ctxb + (size_t)(b * 512 + qb * 64 + w * 16 + lr) * 512 + hh * 64;
#pragma unroll
  for (int mi = 0; mi < 4; ++mi)
#pragma unroll
    for (int vp2 = 0; vp2 < 2; ++vp2) {
      const int dh = mi * 16 + g * 4 + vp2 * 2;
      unsigned int word = (unsigned int)f2bf(oacc[mi][vp2 * 2] * inv) |
                          ((unsigned int)f2bf(oacc[mi][vp2 * 2 + 1] * inv) << 16);
      *(unsigned int*)(op + dh) = word;
    }
}

// ---------------- W_in projection + PE, f32 inputs, bf16 out. 64x64 tile, K=64.
#define OUTER16(ACC, A4, B4) do { \
  ACC[0][0] += (A4).x*(B4).x; ACC[0][1] += (A4).x*(B4).y; ACC[0][2] += (A4).x*(B4).z; ACC[0][3] += (A4).x*(B4).w; \
  ACC[1][0] += (A4).y*(B4).x; ACC[1][1] += (A4).y*(B4).y; ACC[1][2] += (A4).y*(B4).z; ACC[1][3] += (A4).y*(B4).w; \
  ACC[2][0] += (A4).z*(B4).x; ACC[2][1] += (A4).z*(B4).y; ACC[2][2] += (A4).z*(B4).z; ACC[2][3] += (A4).z*(B4).w; \
  ACC[3][0] += (A4).w*(B4).x; ACC[3][1] += (A4).w*(B4).y; ACC[3][2] += (A4).w*(B4).z; ACC[3][3] += (A4).w*(B4).w; \
} while (0)

__global__ __launch_bounds__(256) void win_pe_gemm(const float* __restrict__ A,
                                                   const float* __restrict__ Bm,
                                                   const float* __restrict__ bias,
                                                   const float* __restrict__ peb,
                                                   ushort_t* __restrict__ hbb) {
  __shared__ float As[16][68];
  __shared__ float Bs[16][68];
  const int t = threadIdx.x;
  const int m0 = blockIdx.x << 6;
  const int n0 = blockIdx.y << 6;
  const int r0 = (t >> 4) << 2;
  const int c0 = (t & 15) << 2;
  const int lm = t >> 2;
  const int lk4 = (t & 3) << 2;
  float acc[4][4] = {{0.f, 0.f, 0.f, 0.f}, {0.f, 0.f, 0.f, 0.f},
                     {0.f, 0.f, 0.f, 0.f}, {0.f, 0.f, 0.f, 0.f}};
  for (int kt = 0; kt < 64; kt += 16) {
    __syncthreads();
    float4 av = *reinterpret_cast<const float4*>(A + (size_t)(m0 + lm) * 64 + kt + lk4);
    As[lk4 + 0][lm] = av.x; As[lk4 + 1][lm] = av.y;
    As[lk4 + 2][lm] = av.z; As[lk4 + 3][lm] = av.w;
    float4 bv = *reinterpret_cast<const float4*>(Bm + (size_t)(n0 + lm) * 64 + kt + lk4);
    Bs[lk4 + 0][lm] = bv.x; Bs[lk4 + 1][lm] = bv.y;
    Bs[lk4 + 2][lm] = bv.z; Bs[lk4 + 3][lm] = bv.w;
    __syncthreads();
#pragma unroll
    for (int k = 0; k < 16; ++k) {
      float4 a4 = *reinterpret_cast<const float4*>(&As[k][r0]);
      float4 b4 = *reinterpret_cast<const float4*>(&Bs[k][c0]);
      OUTER16(acc, a4, b4);
    }
  }
  const float bb0 = bias[n0 + c0 + 0], bb1 = bias[n0 + c0 + 1];
  const float bb2 = bias[n0 + c0 + 2], bb3 = bias[n0 + c0 + 3];
#pragma unroll
  for (int i = 0; i < 4; ++i) {
    const int row = m0 + r0 + i;
    float4 p = *reinterpret_cast<const float4*>(peb + (size_t)(row & 511) * 512 + n0 + c0);
    ushort4 ob;
    ob.x = f2bf(acc[i][0] + bb0 + p.x);
    ob.y = f2bf(acc[i][1] + bb1 + p.y);
    ob.z = f2bf(acc[i][2] + bb2 + p.z);
    ob.w = f2bf(acc[i][3] + bb3 + p.w);
    *reinterpret_cast<ushort4*>(hbb + (size_t)row * 512 + n0 + c0) = ob;
  }
}

// ---------------- wave-per-row softmax over 1024 bf16 -> f32 attn + bf16 copy
__global__ __launch_bounds__(256) void softmax_wave(const ushort_t* __restrict__ simsb,
                                                    float* __restrict__ attn,
                                                    ushort_t* __restrict__ attnb) {
  const int t = threadIdx.x;
  const size_t row = (size_t)blockIdx.x * 4 + (t >> 6);
  const int lane = t & 63;
  const size_t base = row * 1024 + lane * 16;
  ushort8 v0 = *reinterpret_cast<const ushort8*>(simsb + base);
  ushort8 v1 = *reinterpret_cast<const ushort8*>(simsb + base + 8);
  float xs[16];
  float mx = -INFINITY;
#pragma unroll
  for (int i = 0; i < 8; ++i) { xs[i] = bf2f(v0[i]); xs[i + 8] = bf2f(v1[i]); }
#pragma unroll
  for (int i = 0; i < 16; ++i) mx = fmaxf(mx, xs[i]);
#pragma unroll
  for (int off = 1; off < 64; off <<= 1) mx = fmaxf(mx, __shfl_xor(mx, off));
  float sum = 0.f;
#pragma unroll
  for (int i = 0; i < 16; ++i) { xs[i] = __expf(xs[i] - mx); sum += xs[i]; }
#pragma unroll
  for (int off = 1; off < 64; off <<= 1) sum += __shfl_xor(sum, off);
  const float inv = 1.f / sum;
  ushort8 o0, o1;
#pragma unroll
  for (int i = 0; i < 16; ++i) xs[i] *= inv;
#pragma unroll
  for (int i = 0; i < 4; ++i) {
    float4 f = make_float4(xs[4 * i], xs[4 * i + 1], xs[4 * i + 2], xs[4 * i + 3]);
    *reinterpret_cast<float4*>(attn + base + 4 * i) = f;
  }
#pragma unroll
  for (int i = 0; i < 8; ++i) { o0[i] = f2bf(xs[i]); o1[i] = f2bf(xs[i + 8]); }
  *reinterpret_cast<ushort8*>(attnb + base) = o0;
  *reinterpret_cast<ushort8*>(attnb + base + 8) = o1;
}

__global__ void pe_kernel(float* __restrict__ pe) {
  const int s = blockIdx.x, i = threadIdx.x;
  double div = exp((double)(2 * i) * (-log(10000.0) / 512.0));
  double a = (double)s * div;
  pe[s * 512 + 2 * i] = (float)sin(a);
  pe[s * 512 + 2 * i + 1] = (float)cos(a);
}

// All weight conversions + fc2 zero-padded to 128 rows.
__global__ __launch_bounds__(256) void cvt_all(
    const float* __restrict__ qkvw, const float* __restrict__ outw,
    const float* __restrict__ ff1w, const float* __restrict__ ff2w,
    const float* __restrict__ memw, const float* __restrict__ fc1w,
    const float* __restrict__ gc1w, const float* __restrict__ gc2w,
    const float* __restrict__ fc2w,
    ushort_t* qkvb, ushort_t* outb, ushort_t* ff1b, ushort_t* ff2b,
    ushort_t* memb, ushort_t* fc1b, ushort_t* gc1b, ushort_t* gc2b,
    ushort_t* fc2p) {
  const int gidx = blockIdx.x * 256 + threadIdx.x;  // < 2768896
  if (gidx >= 2768896) return;
  if (gidx >= 2752512) {
    const int off = gidx - 2752512;
    ushort4 o = {0, 0, 0, 0};
    if (off < 8192) {
      float4 v = reinterpret_cast<const float4*>(fc2w)[off];
      o.x = f2bf(v.x); o.y = f2bf(v.y); o.z = f2bf(v.z); o.w = f2bf(v.w);
    }
    reinterpret_cast<ushort4*>(fc2p)[off] = o;
    return;
  }
  const float* s; ushort_t* d; int off;
  if (gidx < 589824)        { s = qkvw; d = qkvb; off = gidx; }
  else if (gidx < 786432)   { s = outw; d = outb; off = gidx - 589824; }
  else if (gidx < 1572864)  { s = ff1w; d = ff1b; off = gidx - 786432; }
  else if (gidx < 2359296)  { s = ff2w; d = ff2b; off = gidx - 1572864; }
  else if (gidx < 2490368)  { s = memw; d = memb; off = gidx - 2359296; }
  else if (gidx < 2621440)  { s = fc1w; d = fc1b; off = gidx - 2490368; }
  else if (gidx < 2686976)  { s = gc1w; d = gc1b; off = gidx - 2621440; }
  else                      { s = gc2w; d = gc2b; off = gidx - 2686976; }
  float4 v = reinterpret_cast<const float4*>(s)[off];
  ushort4 o;
  o.x = f2bf(v.x); o.y = f2bf(v.y); o.z = f2bf(v.z); o.w = f2bf(v.w);
  reinterpret_cast<ushort4*>(d)[off] = o;
}

__global__ __launch_bounds__(256) void transpose_cvt(const float* __restrict__ in,
                                                     ushort_t* __restrict__ out) {
  const int g = blockIdx.x * 256 + threadIdx.x;
  const int r = g >> 9, c = g & 511;
  out[(size_t)c * 1024 + r] = f2bf(in[g]);
}

__global__ __launch_bounds__(256) void transpose_x_bf16(const float* __restrict__ x,
                                                        ushort_t* __restrict__ xtb) {
  __shared__ float Ls[64][65];
  const int sc = blockIdx.x, b = blockIdx.y;
  const int t = threadIdx.x;
  const int f = t & 63, sr = t >> 6;
#pragma unroll
  for (int j = 0; j < 16; ++j) {
    const int s = sr + 4 * j;
    Ls[s][f] = x[((size_t)(b * 512 + sc * 64 + s)) * 64 + f];
  }
  __syncthreads();
#pragma unroll
  for (int j = 0; j < 16; ++j) {
    const int fr = sr * 16 + j;
    xtb[((size_t)b * 64 + fr) * 512 + sc * 64 + f] = f2bf(Ls[f][fr]);
  }
}

// fmean + graph fused: one block per batch (256 threads).
__global__ __launch_bounds__(256) void fmean_graph(const float* __restrict__ x,
                                                   float* __restrict__ An) {
  __shared__ float part[4][64];
  __shared__ float fv[64];
  __shared__ float Am[64][65];
  const int b = blockIdx.x, t = threadIdx.x;
  const int f = t & 63, sg = t >> 6;
  const int i = t >> 2, g = t & 3;
  float acc = 0.f;
  const float* xp = x + ((size_t)b * 512 + sg) * 64 + f;
  for (int s = sg; s < 512; s += 4, xp += 256) acc += *xp;
  part[sg][f] = acc;
#pragma unroll
  for (int j = 0; j < 16; ++j) Am[i][g * 16 + j] = 0.f;
  __syncthreads();
  if (t < 64) {
    float m = (part[0][t] + part[1][t] + part[2][t] + part[3][t]) * (1.f / 512.f);
    float ss = m * m;
#pragma unroll
    for (int off = 32; off; off >>= 1) ss += __shfl_xor(ss, off);
    float n = fmaxf(sqrtf(ss), 1e-12f);
    fv[t] = m / n;
  }
  __syncthreads();
  const float fi = fv[i];
  unsigned int mask = 0;
  int sel[4];
  for (int r = 0; r < 4; ++r) {
    float best = -INFINITY;
    int bi = 1 << 30;
    for (int j = 0; j < 16; ++j) {
      if (mask & (1u << j)) continue;
      float v = fi * fv[g * 16 + j];
      if (v > best) { best = v; bi = g * 16 + j; }
    }
#pragma unroll
    for (int off = 1; off < 4; off <<= 1) {
      float ov = __shfl_xor(best, off);
      int oi = __shfl_xor(bi, off);
      if (ov > best || (ov == best && oi < bi)) { best = ov; bi = oi; }
    }
    sel[r] = bi;
    if ((bi >> 4) == g) mask |= 1u << (bi & 15);
  }
  if (g == 0) { Am[i][sel[1]] = 1.f; Am[i][sel[2]] = 1.f; Am[i][sel[3]] = 1.f; }
  __syncthreads();
  float vals[16];
  float deg = 0.f;
#pragma unroll
  for (int j0 = 0; j0 < 16; ++j0) {
    const int j = g * 16 + j0;
    float v = (j == i) ? 1.f : fmaxf(Am[i][j], Am[j][i]);
    vals[j0] = v;
    deg += v;
  }
#pragma unroll
  for (int off = 1; off < 4; off <<= 1) deg += __shfl_xor(deg, off);
  const float inv = 1.f / deg;
  float* out = An + ((size_t)b * 64 + i) * 64 + g * 16;
#pragma unroll
  for (int j0 = 0; j0 < 16; ++j0) out[j0] = vals[j0] * inv;
}

template <bool RELU, bool STORE_T>
__global__ __launch_bounds__(256) void bmm_an(const float* __restrict__ An,
                                              const float* __restrict__ X,
                                              float* __restrict__ Y,
                                              ushort_t* __restrict__ Yb) {
  __shared__ float Ag[64][68];
  __shared__ float Xs[64][68];
  const int nc = blockIdx.x << 6;
  const int b = blockIdx.y;
  const int t = threadIdx.x;
  {
    const int i = t >> 2, g0 = (t & 3) << 4;
    const float* ap = An + ((size_t)b * 64 + i) * 64 + g0;
#pragma unroll
    for (int j = 0; j < 16; ++j) Ag[g0 + j][i] = ap[j];
  }
  {
    const int g = t >> 2, n4 = (t & 3) << 4;
    const float* xp = X + ((size_t)b * 64 + g) * 512 + nc + n4;
#pragma unroll
    for (int j = 0; j < 4; ++j)
      *reinterpret_cast<float4*>(&Xs[g][n4 + 4 * j]) =
          *reinterpret_cast<const float4*>(xp + 4 * j);
  }
  __syncthreads();
  const int r0 = (t >> 4) << 2, c0 = (t & 15) << 2;
  float acc[4][4] = {{0.f, 0.f, 0.f, 0.f}, {0.f, 0.f, 0.f, 0.f},
                     {0.f, 0.f, 0.f, 0.f}, {0.f, 0.f, 0.f, 0.f}};
#pragma unroll 8
  for (int g = 0; g < 64; ++g) {
    float4 a4 = *reinterpret_cast<const float4*>(&Ag[g][r0]);
    float4 x4 = *reinterpret_cast<const float4*>(&Xs[g][c0]);
    OUTER16(acc, a4, x4);
  }
  if (!STORE_T) {
#pragma unroll
    for (int i = 0; i < 4; ++i) {
      float4 o = make_float4(acc[i][0], acc[i][1], acc[i][2], acc[i][3]);
      if (RELU) {
        o.x = fmaxf(o.x, 0.f); o.y = fmaxf(o.y, 0.f);
        o.z = fmaxf(o.z, 0.f); o.w = fmaxf(o.w, 0.f);
      }
      ushort4 ob;
      ob.x = f2bf(o.x); ob.y = f2bf(o.y); ob.z = f2bf(o.z); ob.w = f2bf(o.w);
      *reinterpret_cast<ushort4*>(Yb + ((size_t)b * 64 + r0 + i) * 512 + nc + c0) = ob;
    }
  } else {
#pragma unroll
    for (int j = 0; j < 4; ++j) {
      float4 o = make_float4(acc[0][j], acc[1][j], acc[2][j], acc[3][j]);
      *reinterpret_cast<float4*>(Y + ((size_t)b * 512 + nc + c0 + j) * 64 + r0) = o;
    }
  }
}

}  // namespace

extern "C" void kernel_launch(void* const* d_in, const int* in_sizes, int n_in,
                              void* d_out, int out_size, void* d_ws, size_t ws_size,
                              hipStream_t stream) {
  const float* x     = (const float*)d_in[0];
  const float* W_in  = (const float*)d_in[1];
  const float* b_in  = (const float*)d_in[2];
  const float* qkv_w = (const float*)d_in[3];
  const float* qkv_b = (const float*)d_in[4];
  const float* out_w = (const float*)d_in[5];
  const float* out_b = (const float*)d_in[6];
  const float* ln1_g = (const float*)d_in[7];
  const float* ln1_b = (const float*)d_in[8];
  const float* ln2_g = (const float*)d_in[9];
  const float* ln2_b = (const float*)d_in[10];
  const float* ff1_w = (const float*)d_in[11];
  const float* ff1_b = (const float*)d_in[12];
  const float* ff2_w = (const float*)d_in[13];
  const float* ff2_b = (const float*)d_in[14];
  const float* memw  = (const float*)d_in[15];
  const float* fc1_w = (const float*)d_in[16];
  const float* fc1_b = (const float*)d_in[17];
  const float* fc2_w = (const float*)d_in[18];
  const float* fc2_b = (const float*)d_in[19];
  const float* gc1_w = (const float*)d_in[20];
  const float* gc1_b = (const float*)d_in[21];
  const float* gc2_w = (const float*)d_in[22];
  const float* gc2_b = (const float*)d_in[23];

  char* wsb = (char*)d_ws;
  ushort_t* hb     = (ushort_t*)(wsb + 0);            // 16MB
  ushort_t* ctxb   = (ushort_t*)(wsb + 16 * MB);      // 16MB
  char*     U1     = wsb + 48 * MB;                   // 96MB shared region
  float*    pe     = (float*)(wsb + 144 * MB);        // 1MB
  ushort_t* qkv_wb = (ushort_t*)(wsb + 146 * MB);     // 4.5MB
  ushort_t* out_wb = (ushort_t*)(wsb + 151 * MB);     // 1.5MB
  ushort_t* ff1_wb = (ushort_t*)(wsb + 153 * MB);     // 6MB
  ushort_t* ff2_wb = (ushort_t*)(wsb + 160 * MB);     // 6MB
  ushort_t* mem_b  = (ushort_t*)(wsb + 166 * MB);     // 1MB
  ushort_t* memT_b = (ushort_t*)(wsb + 167 * MB);     // 1MB
  ushort_t* fc1_wb = (ushort_t*)(wsb + 168 * MB);     // 1MB
  ushort_t* gc1_wb = (ushort_t*)(wsb + 169 * MB);     // 0.5MB
  ushort_t* gc2_wb = (ushort_t*)(wsb + 169 * MB + 524288);  // 0.5MB
  ushort_t* fc2_wp = (ushort_t*)(wsb + 170 * MB);     // 128KB (128x512 padded)
  float*    An     = (float*)(wsb + 172 * MB);        // 512KB

  // U1 overlays (sequentially dead):
  ushort_t* qkvb    = (ushort_t*)U1;                  // 48MB per-layer qkv
  ushort_t* midb    = (ushort_t*)U1;                  // 64MB ff1 out
  ushort_t* catb    = (ushort_t*)U1;                  // 32MB [h|upd] (layer-3 on)
  ushort_t* simsb   = (ushort_t*)(U1 + 32 * MB);      // 32MB sims bf16
  ushort_t* attnb   = (ushort_t*)(U1 + 64 * MB);      // 32MB softmax bf16
  ushort_t* fc1outb = (ushort_t*)(U1 + 64 * MB);      // 16MB (after upd; attnb dead)
  // GCN scratch (after fc2):
  ushort_t* xtb  = (ushort_t*)U1;                      // 2MB
  float*    t1   = (float*)(U1 + 2 * MB);              // 4MB
  ushort_t* h1b  = (ushort_t*)(U1 + 6 * MB);           // 2MB
  float*    t2   = (float*)(U1 + 8 * MB);              // 4MB

  float* t_out = (float*)d_out;
  float* g_out = t_out + 1048576;
  float* attn  = g_out + 1048576;

  // ---- conversions / tables
  hipLaunchKernelGGL(cvt_all, dim3(10816), dim3(256), 0, stream,
                     qkv_w, out_w, ff1_w, ff2_w, memw, fc1_w, gc1_w, gc2_w, fc2_w,
                     qkv_wb, out_wb, ff1_wb, ff2_wb, mem_b, fc1_wb, gc1_wb, gc2_wb,
                     fc2_wp);
  hipLaunchKernelGGL(transpose_cvt, dim3(2048), dim3(256), 0, stream, memw, memT_b);
  hipLaunchKernelGGL(pe_kernel, dim3(512), dim3(256), 0, stream, pe);

  // ---- input projection + PE (bf16 out)
  hipLaunchKernelGGL(win_pe_gemm, dim3(256, 8), dim3(256), 0, stream,
                     x, W_in, b_in, pe, hb);

  for (int l = 0; l < 3; ++l) {
    hipLaunchKernelGGL((gemm256<false, true>), dim3(64, 6), dim3(512), 0, stream,
                       hb, qkv_wb + (size_t)l * 786432, qkv_b + l * 1536, qkvb,
                       512, 512, 1536);
    hipLaunchKernelGGL(flash_attn_mfma, dim3(8, 8, 32), dim3(256), 0, stream, qkvb, ctxb);
    // out-proj + residual + LN1 fused (in-place hb update)
    hipLaunchKernelGGL(gemm_ln, dim3(256), dim3(512), 0, stream,
                       ctxb, out_wb + (size_t)l * 262144, out_b + l * 512,
                       hb, ln1_g + l * 512, ln1_b + l * 512, hb, 512, 512, 512);
    hipLaunchKernelGGL((gemm256<true, true>), dim3(64, 8), dim3(512), 0, stream,
                       hb, ff1_wb + (size_t)l * 1048576, ff1_b + l * 2048, midb,
                       512, 512, 2048);
    // ff2 + residual + LN2 fused (layer 3 writes into cat layout)
    hipLaunchKernelGGL(gemm_ln, dim3(256), dim3(512), 0, stream,
                       midb, ff2_wb + (size_t)l * 1048576, ff2_b + l * 512,
                       hb, ln2_g + l * 512, ln2_b + l * 512,
                       (l < 2) ? hb : catb, 2048, 2048, (l < 2) ? 512 : 1024);
  }

  // ---- memory attention head
  hipLaunchKernelGGL((gemm256<false, true>), dim3(64, 4), dim3(512), 0, stream,
                     catb, mem_b, (const float*)nullptr, simsb,
                     512, 1024, 1024);
  hipLaunchKernelGGL(softmax_wave, dim3(Mrows / 4), dim3(256), 0, stream,
                     simsb, attn, attnb);
  hipLaunchKernelGGL((gemm_bf16<false, true>), dim3(128, 4), dim3(256), 0, stream,
                     attnb, memT_b, (const float*)nullptr, catb + 512,
                     1024, 1024, 1024, 512);
  hipLaunchKernelGGL((gemm_bf16<true, true>), dim3(128, 4), dim3(256), 0, stream,
                     catb, fc1_wb, fc1_b, fc1outb, 1024, 1024, 512, 512);
  hipLaunchKernelGGL((gemm_bf16<false, false>), dim3(128, 1), dim3(256), 0, stream,
                     fc1outb, fc2_wp, fc2_b, t_out, 512, 512, 64, 64);

  // ---- GCN branch
  hipLaunchKernelGGL(fmean_graph, dim3(32), dim3(256), 0, stream, x, An);
  hipLaunchKernelGGL(transpose_x_bf16, dim3(8, 32), dim3(256), 0, stream, x, xtb);
  hipLaunchKernelGGL((gemm_bf16<false, false>), dim3(16, 4), dim3(256), 0, stream,
                     xtb, gc1_wb, gc1_b, t1, 512, 512, 512, 512);
  hipLaunchKernelGGL((bmm_an<true, false>), dim3(8, 32), dim3(256), 0, stream,
                     An, t1, (float*)nullptr, h1b);
  hipLaunchKernelGGL((gemm_bf16<false, false>), dim3(16, 4), dim3(256), 0, stream,
                     h1b, gc2_wb, gc2_b, t2, 512, 512, 512, 512);
  hipLaunchKernelGGL((bmm_an<false, true>), dim3(8, 32), dim3(256), 0, stream,
                     An, t2, g_out, (ushort_t*)nullptr);
}

// Round 12
// 884.531 us; speedup vs baseline: 1.0873x; 1.0873x over previous
//
#include <hip/hip_runtime.h>
#include <hip/hip_bf16.h>
#include <math.h>

// METG forward. Round 12: best-measured composition. gemm256 = round-8 2-deep
// counted-vmcnt; flash = round-9 QB=64 grid (h,qb,b); separate ln_wave
// (gemm_ln fusion regressed: B-panel re-read per M64 block); fmean_graph fused.
// Shapes: B=32 S=512 F_IN=64 D=512 DFF=2048 MEM=1024 L=3 H=8 DH=64

namespace {

typedef unsigned short ushort_t;
using bf16x8 = __attribute__((ext_vector_type(8))) __bf16;
using f32x4 = __attribute__((ext_vector_type(4))) float;
using ushort8 = __attribute__((ext_vector_type(8))) unsigned short;

constexpr int Mrows = 32 * 512;  // 16384
constexpr size_t MB = 1048576;

__device__ __forceinline__ unsigned short f2bf(float f) {
  unsigned int u = __builtin_bit_cast(unsigned int, f);
  u += 0x7fffu + ((u >> 16) & 1u);
  return (unsigned short)(u >> 16);
}
__device__ __forceinline__ float bf2f(ushort_t u) {
  unsigned int v = ((unsigned int)u) << 16;
  return __builtin_bit_cast(float, v);
}

__device__ __forceinline__ void g2lds16(const void* g, void* l) {
  __builtin_amdgcn_global_load_lds(
      (const __attribute__((address_space(1))) unsigned int*)g,
      (__attribute__((address_space(3))) unsigned int*)l, 16, 0, 0);
}

// ---------------- gemm256 (round-8): 256x256 tile, 8 waves, dbuf LDS,
// counted vmcnt(8) + raw s_barrier (no drain in K-loop).
template <bool RELU, bool BF16OUT>
__global__ __launch_bounds__(512, 2) void gemm256(const ushort_t* __restrict__ A,
                                                  const ushort_t* __restrict__ B,
                                                  const float* __restrict__ bias,
                                                  void* __restrict__ Cv,
                                                  int K, int lda, int ldc) {
  __shared__ __align__(16) ushort_t As[2][256 * 64];
  __shared__ __align__(16) ushort_t Bs[2][256 * 64];
  const int t = threadIdx.x;
  const int w = t >> 6, l = t & 63;
  const int m0 = blockIdx.x << 8, n0 = blockIdx.y << 8;
  const int srow8 = l >> 3;
  const int scol = ((l & 7) ^ srow8) << 3;
  const ushort_t* agp = A + (size_t)(m0 + w * 32 + srow8) * lda + scol;
  const ushort_t* bgp = B + (size_t)(n0 + w * 32 + srow8) * K + scol;
  const int wr = w >> 2, wcn = w & 3;
  const int lr = l & 15, g = l >> 4;
  const int sw = (l & 7) << 4;
  const int nt = K >> 6;
  f32x4 acc[8][4] = {};
#pragma unroll
  for (int i = 0; i < 4; ++i) {
    g2lds16(agp + (size_t)(i * 8) * lda, &As[0][(w * 32 + i * 8) * 64]);
    g2lds16(bgp + (size_t)(i * 8) * K, &Bs[0][(w * 32 + i * 8) * 64]);
  }
#pragma unroll
  for (int i = 0; i < 4; ++i) {
    g2lds16(agp + (size_t)(i * 8) * lda + 64, &As[1][(w * 32 + i * 8) * 64]);
    g2lds16(bgp + (size_t)(i * 8) * K + 64, &Bs[1][(w * 32 + i * 8) * 64]);
  }
  for (int j = 0; j < nt; ++j) {
    const int c = j & 1;
    asm volatile("s_waitcnt vmcnt(8)" ::: "memory");
    __builtin_amdgcn_s_barrier();
    asm volatile("" ::: "memory");
    const char* abase = (const char*)&As[c][0];
    const char* bbase = (const char*)&Bs[c][0];
#pragma unroll
    for (int ki = 0; ki < 2; ++ki) {
      const int kb = (ki * 64 + g * 16) ^ sw;
      bf16x8 af[8], bfr[4];
#pragma unroll
      for (int mi = 0; mi < 8; ++mi)
        af[mi] = *(const bf16x8*)(abase + (wr * 128 + mi * 16 + lr) * 128 + kb);
#pragma unroll
      for (int ni = 0; ni < 4; ++ni)
        bfr[ni] = *(const bf16x8*)(bbase + (wcn * 64 + ni * 16 + lr) * 128 + kb);
      __builtin_amdgcn_s_setprio(1);
#pragma unroll
      for (int mi = 0; mi < 8; ++mi)
#pragma unroll
        for (int ni = 0; ni < 4; ++ni)
          acc[mi][ni] = __builtin_amdgcn_mfma_f32_16x16x32_bf16(af[mi], bfr[ni],
                                                                acc[mi][ni], 0, 0, 0);
      __builtin_amdgcn_s_setprio(0);
    }
    asm volatile("s_waitcnt lgkmcnt(0)" ::: "memory");
    __builtin_amdgcn_s_barrier();
    asm volatile("" ::: "memory");
    if (j + 2 < nt) {
      const size_t ko = (size_t)(j + 2) * 64;
#pragma unroll
      for (int i = 0; i < 4; ++i) {
        g2lds16(agp + (size_t)(i * 8) * lda + ko, &As[c][(w * 32 + i * 8) * 64]);
        g2lds16(bgp + (size_t)(i * 8) * K + ko, &Bs[c][(w * 32 + i * 8) * 64]);
      }
    }
  }
  float bb[4];
#pragma unroll
  for (int ni = 0; ni < 4; ++ni) {
    const int ci = n0 + wcn * 64 + ni * 16 + lr;
    bb[ni] = bias ? bias[ci] : 0.f;
  }
  const int crow0 = m0 + wr * 128 + g * 4;
#pragma unroll
  for (int mi = 0; mi < 8; ++mi)
#pragma unroll
    for (int ni = 0; ni < 4; ++ni) {
      const int ci = n0 + wcn * 64 + ni * 16 + lr;
#pragma unroll
      for (int v = 0; v < 4; ++v) {
        float val = acc[mi][ni][v] + bb[ni];
        if (RELU) val = fmaxf(val, 0.f);
        const size_t off = (size_t)(crow0 + mi * 16 + v) * ldc + ci;
        if (BF16OUT) ((ushort_t*)Cv)[off] = f2bf(val);
        else         ((float*)Cv)[off] = val;
      }
    }
}

// ---------------- bf16 MFMA GEMM 128x128 (round-4 proven structure)
template <bool RELU, bool BF16OUT>
__global__ __launch_bounds__(256) void gemm_bf16(const ushort_t* __restrict__ A,
                                                 const ushort_t* __restrict__ B,
                                                 const float* __restrict__ bias,
                                                 void* __restrict__ Cv,
                                                 int K, int lda, int ldc, int Nclip) {
  __shared__ __align__(16) ushort_t As[128 * 64];
  __shared__ __align__(16) ushort_t Bs[128 * 64];
  const int t = threadIdx.x;
  const int w = t >> 6, l = t & 63;
  const int m0 = blockIdx.x << 7, n0 = blockIdx.y << 7;
  const int srow8 = l >> 3;
  const int scol = ((l & 7) ^ srow8) << 3;
  const ushort_t* agp = A + (size_t)(m0 + w * 32 + srow8) * lda + scol;
  const ushort_t* bgp = B + (size_t)(n0 + w * 32 + srow8) * K + scol;
  ushort_t* alds = &As[(w * 32) * 64];
  ushort_t* blds = &Bs[(w * 32) * 64];
  const int wr = w >> 1, wc = w & 1;
  const int lr = l & 15, g = l >> 4;
  const int sw = (l & 7) << 4;
  f32x4 acc[4][4] = {};
  for (int kt = 0; kt < K; kt += 64) {
    __syncthreads();
#pragma unroll
    for (int i = 0; i < 4; ++i) {
      g2lds16(agp + (size_t)(i * 8) * lda + kt, alds + i * 8 * 64);
      g2lds16(bgp + (size_t)(i * 8) * K + kt, blds + i * 8 * 64);
    }
    __syncthreads();
#pragma unroll
    for (int ki = 0; ki < 2; ++ki) {
      bf16x8 af[4], bf[4];
      const int kb = (ki * 64 + g * 16) ^ sw;
#pragma unroll
      for (int mi = 0; mi < 4; ++mi)
        af[mi] = *(const bf16x8*)((const char*)As + (wr * 64 + mi * 16 + lr) * 128 + kb);
#pragma unroll
      for (int ni = 0; ni < 4; ++ni)
        bf[ni] = *(const bf16x8*)((const char*)Bs + (wc * 64 + ni * 16 + lr) * 128 + kb);
#pragma unroll
      for (int mi = 0; mi < 4; ++mi)
#pragma unroll
        for (int ni = 0; ni < 4; ++ni)
          acc[mi][ni] = __builtin_amdgcn_mfma_f32_16x16x32_bf16(af[mi], bf[ni],
                                                                acc[mi][ni], 0, 0, 0);
    }
  }
  float bb[4];
#pragma unroll
  for (int ni = 0; ni < 4; ++ni) {
    const int ci = n0 + wc * 64 + ni * 16 + lr;
    bb[ni] = (bias && ci < Nclip) ? bias[ci] : 0.f;
  }
  const int crow0 = m0 + wr * 64 + g * 4;
#pragma unroll
  for (int mi = 0; mi < 4; ++mi)
#pragma unroll
    for (int ni = 0; ni < 4; ++ni) {
      const int ci = n0 + wc * 64 + ni * 16 + lr;
      if (ci >= Nclip) continue;
#pragma unroll
      for (int v = 0; v < 4; ++v) {
        float val = acc[mi][ni][v] + bb[ni];
        if (RELU) val = fmaxf(val, 0.f);
        const size_t off = (size_t)(crow0 + mi * 16 + v) * ldc + ci;
        if (BF16OUT) ((ushort_t*)Cv)[off] = f2bf(val);
        else         ((float*)Cv)[off] = val;
      }
    }
}

// ---------------- bf16 MFMA flash attention (QB=64, grid (h,qb,b))
__global__ __launch_bounds__(256) void flash_attn_mfma(const ushort_t* __restrict__ qkvb,
                                                       ushort_t* __restrict__ ctxb) {
  __shared__ __align__(16) ushort_t Qs[64 * 64];
  __shared__ __align__(16) ushort_t Ks[64 * 64];
  __shared__ __align__(16) ushort_t VT[64 * 64];
  __shared__ __align__(16) ushort_t Ps[64 * 64];
  const int hh = blockIdx.x, qb = blockIdx.y, b = blockIdx.z;
  const int t = threadIdx.x, w = t >> 6, l = t & 63;
  const int g = l >> 4, lr = l & 15, l7 = l & 7;
  const ushort_t* qkv0 = qkvb + (size_t)b * 512 * 1536 + hh * 64;
  {
    const int r8 = l >> 3;
    const int gcol = (l7 ^ r8) << 3;
#pragma unroll
    for (int i = 0; i < 2; ++i) {
      const int row = w * 16 + i * 8 + r8;
      g2lds16(qkv0 + (size_t)(qb * 64 + row) * 1536 + gcol, &Qs[(w * 16 + i * 8) * 64]);
    }
  }
  float mst = -INFINITY, lst = 0.f;
  f32x4 oacc[4] = {};
  const int vk0 = (t & 31) * 2;
  const int vdh0 = (t >> 5) * 8;
  for (int kt = 0; kt < 8; ++kt) {
    __syncthreads();
    {
      const int r8 = l >> 3;
      const int gcol = (l7 ^ r8) << 3;
#pragma unroll
      for (int i = 0; i < 2; ++i) {
        const int row = w * 16 + i * 8 + r8;
        g2lds16(qkv0 + 512 + (size_t)(kt * 64 + row) * 1536 + gcol,
                &Ks[(w * 16 + i * 8) * 64]);
      }
    }
    {
      const ushort_t* vp = qkv0 + 1024 + (size_t)(kt * 64 + vk0) * 1536 + vdh0;
      ushort8 v0 = *(const ushort8*)vp;
      ushort8 v1 = *(const ushort8*)(vp + 1536);
      const int slotbase = vk0 >> 3;
      const int inb = (vk0 & 7) * 2;
#pragma unroll
      for (int e = 0; e < 8; ++e) {
        const int dh = vdh0 + e;
        unsigned int word = (unsigned int)v0[e] | ((unsigned int)v1[e] << 16);
        *(unsigned int*)((char*)VT + dh * 128 + (((slotbase ^ (dh & 7)) << 4) + inb)) = word;
      }
    }
    __syncthreads();
    f32x4 sacc[4] = {};
#pragma unroll
    for (int ki = 0; ki < 2; ++ki) {
      const int sb = ((ki * 4 + g) ^ l7) << 4;
      bf16x8 qf = *(const bf16x8*)((const char*)Qs + (w * 16 + lr) * 128 + sb);
#pragma unroll
      for (int mi = 0; mi < 4; ++mi) {
        bf16x8 kf = *(const bf16x8*)((const char*)Ks + (mi * 16 + lr) * 128 + sb);
        sacc[mi] = __builtin_amdgcn_mfma_f32_16x16x32_bf16(kf, qf, sacc[mi], 0, 0, 0);
      }
    }
    float p[4][4];
    float cmax = -INFINITY;
#pragma unroll
    for (int mi = 0; mi < 4; ++mi)
#pragma unroll
      for (int v = 0; v < 4; ++v) {
        p[mi][v] = sacc[mi][v] * 0.125f;
        cmax = fmaxf(cmax, p[mi][v]);
      }
    cmax = fmaxf(cmax, __shfl_xor(cmax, 16));
    cmax = fmaxf(cmax, __shfl_xor(cmax, 32));
    const float mnew = fmaxf(mst, cmax);
    const float al = __expf(mst - mnew);
    float csum = 0.f;
#pragma unroll
    for (int mi = 0; mi < 4; ++mi)
#pragma unroll
      for (int v = 0; v < 4; ++v) {
        p[mi][v] = __expf(p[mi][v] - mnew);
        csum += p[mi][v];
      }
    csum += __shfl_xor(csum, 16);
    csum += __shfl_xor(csum, 32);
    lst = lst * al + csum;
    mst = mnew;
#pragma unroll
    for (int mi = 0; mi < 4; ++mi) oacc[mi] *= al;
    {
      char* pbase = (char*)Ps + (w * 16 + lr) * 128;
#pragma unroll
      for (int mi = 0; mi < 4; ++mi)
#pragma unroll
        for (int vp2 = 0; vp2 < 2; ++vp2) {
          const int klo = mi * 16 + g * 4 + vp2 * 2;
          unsigned int word = (unsigned int)f2bf(p[mi][vp2 * 2]) |
                              ((unsigned int)f2bf(p[mi][vp2 * 2 + 1]) << 16);
          *(unsigned int*)(pbase + (((klo >> 3) ^ l7) << 4) + (klo & 7) * 2) = word;
        }
    }
#pragma unroll
    for (int ki = 0; ki < 2; ++ki) {
      const int sb = ((ki * 4 + g) ^ l7) << 4;
      bf16x8 pf = *(const bf16x8*)((const char*)Ps + (w * 16 + lr) * 128 + sb);
#pragma unroll
      for (int mi = 0; mi < 4; ++mi) {
        bf16x8 vf = *(const bf16x8*)((const char*)VT + (mi * 16 + lr) * 128 + sb);
        oacc[mi] = __builtin_amdgcn_mfma_f32_16x16x32_bf16(vf, pf, oacc[mi], 0, 0, 0);
      }
    }
  }
  const float inv = 1.f / lst;
  ushort_t* op = ctxb + (size_t)(b * 512 + qb * 64 + w * 16 + lr) * 512 + hh * 64;
#pragma unroll
  for (int mi = 0; mi < 4; ++mi)
#pragma unroll
    for (int vp2 = 0; vp2 < 2; ++vp2) {
      const int dh = mi * 16 + g * 4 + vp2 * 2;
      unsigned int word = (unsigned int)f2bf(oacc[mi][vp2 * 2] * inv) |
                          ((unsigned int)f2bf(oacc[mi][vp2 * 2 + 1] * inv) << 16);
      *(unsigned int*)(op + dh) = word;
    }
}

// ---------------- W_in projection + PE, f32 inputs, bf16 out. 64x64 tile, K=64.
#define OUTER16(ACC, A4, B4) do { \
  ACC[0][0] += (A4).x*(B4).x; ACC[0][1] += (A4).x*(B4).y; ACC[0][2] += (A4).x*(B4).z; ACC[0][3] += (A4).x*(B4).w; \
  ACC[1][0] += (A4).y*(B4).x; ACC[1][1] += (A4).y*(B4).y; ACC[1][2] += (A4).y*(B4).z; ACC[1][3] += (A4).y*(B4).w; \
  ACC[2][0] += (A4).z*(B4).x; ACC[2][1] += (A4).z*(B4).y; ACC[2][2] += (A4).z*(B4).z; ACC[2][3] += (A4).z*(B4).w; \
  ACC[3][0] += (A4).w*(B4).x; ACC[3][1] += (A4).w*(B4).y; ACC[3][2] += (A4).w*(B4).z; ACC[3][3] += (A4).w*(B4).w; \
} while (0)

__global__ __launch_bounds__(256) void win_pe_gemm(const float* __restrict__ A,
                                                   const float* __restrict__ Bm,
                                                   const float* __restrict__ bias,
                                                   const float* __restrict__ peb,
                                                   ushort_t* __restrict__ hbb) {
  __shared__ float As[16][68];
  __shared__ float Bs[16][68];
  const int t = threadIdx.x;
  const int m0 = blockIdx.x << 6;
  const int n0 = blockIdx.y << 6;
  const int r0 = (t >> 4) << 2;
  const int c0 = (t & 15) << 2;
  const int lm = t >> 2;
  const int lk4 = (t & 3) << 2;
  float acc[4][4] = {{0.f, 0.f, 0.f, 0.f}, {0.f, 0.f, 0.f, 0.f},
                     {0.f, 0.f, 0.f, 0.f}, {0.f, 0.f, 0.f, 0.f}};
  for (int kt = 0; kt < 64; kt += 16) {
    __syncthreads();
    float4 av = *reinterpret_cast<const float4*>(A + (size_t)(m0 + lm) * 64 + kt + lk4);
    As[lk4 + 0][lm] = av.x; As[lk4 + 1][lm] = av.y;
    As[lk4 + 2][lm] = av.z; As[lk4 + 3][lm] = av.w;
    float4 bv = *reinterpret_cast<const float4*>(Bm + (size_t)(n0 + lm) * 64 + kt + lk4);
    Bs[lk4 + 0][lm] = bv.x; Bs[lk4 + 1][lm] = bv.y;
    Bs[lk4 + 2][lm] = bv.z; Bs[lk4 + 3][lm] = bv.w;
    __syncthreads();
#pragma unroll
    for (int k = 0; k < 16; ++k) {
      float4 a4 = *reinterpret_cast<const float4*>(&As[k][r0]);
      float4 b4 = *reinterpret_cast<const float4*>(&Bs[k][c0]);
      OUTER16(acc, a4, b4);
    }
  }
  const float bb0 = bias[n0 + c0 + 0], bb1 = bias[n0 + c0 + 1];
  const float bb2 = bias[n0 + c0 + 2], bb3 = bias[n0 + c0 + 3];
#pragma unroll
  for (int i = 0; i < 4; ++i) {
    const int row = m0 + r0 + i;
    float4 p = *reinterpret_cast<const float4*>(peb + (size_t)(row & 511) * 512 + n0 + c0);
    ushort4 ob;
    ob.x = f2bf(acc[i][0] + bb0 + p.x);
    ob.y = f2bf(acc[i][1] + bb1 + p.y);
    ob.z = f2bf(acc[i][2] + bb2 + p.z);
    ob.w = f2bf(acc[i][3] + bb3 + p.w);
    *reinterpret_cast<ushort4*>(hbb + (size_t)row * 512 + n0 + c0) = ob;
  }
}

// ---------------- wave-per-row LN
__global__ __launch_bounds__(256) void ln_wave(const ushort_t* __restrict__ hbi,
                                               const ushort_t* __restrict__ resb,
                                               const float* __restrict__ g,
                                               const float* __restrict__ bt,
                                               ushort_t* __restrict__ hbo, int hbs) {
  const int t = threadIdx.x;
  const size_t row = (size_t)blockIdx.x * 4 + (t >> 6);
  const int lane = t & 63;
  const size_t base = row * 512 + lane * 8;
  ushort8 hv = *reinterpret_cast<const ushort8*>(hbi + base);
  ushort8 rv = *reinterpret_cast<const ushort8*>(resb + base);
  float xs[8];
  float sum = 0.f;
#pragma unroll
  for (int i = 0; i < 8; ++i) { xs[i] = bf2f(hv[i]) + bf2f(rv[i]); sum += xs[i]; }
#pragma unroll
  for (int off = 1; off < 64; off <<= 1) sum += __shfl_xor(sum, off);
  const float mean = sum * (1.f / 512.f);
  float vs = 0.f;
#pragma unroll
  for (int i = 0; i < 8; ++i) { xs[i] -= mean; vs += xs[i] * xs[i]; }
#pragma unroll
  for (int off = 1; off < 64; off <<= 1) vs += __shfl_xor(vs, off);
  const float rstd = rsqrtf(vs * (1.f / 512.f) + 1e-5f);
  float4 g0 = *reinterpret_cast<const float4*>(g + lane * 8);
  float4 g1 = *reinterpret_cast<const float4*>(g + lane * 8 + 4);
  float4 b0 = *reinterpret_cast<const float4*>(bt + lane * 8);
  float4 b1 = *reinterpret_cast<const float4*>(bt + lane * 8 + 4);
  ushort8 o;
  o[0] = f2bf(xs[0] * rstd * g0.x + b0.x); o[1] = f2bf(xs[1] * rstd * g0.y + b0.y);
  o[2] = f2bf(xs[2] * rstd * g0.z + b0.z); o[3] = f2bf(xs[3] * rstd * g0.w + b0.w);
  o[4] = f2bf(xs[4] * rstd * g1.x + b1.x); o[5] = f2bf(xs[5] * rstd * g1.y + b1.y);
  o[6] = f2bf(xs[6] * rstd * g1.z + b1.z); o[7] = f2bf(xs[7] * rstd * g1.w + b1.w);
  *reinterpret_cast<ushort8*>(hbo + row * hbs + lane * 8) = o;
}

// ---------------- wave-per-row softmax over 1024 bf16 -> f32 attn + bf16 copy
__global__ __launch_bounds__(256) void softmax_wave(const ushort_t* __restrict__ simsb,
                                                    float* __restrict__ attn,
                                                    ushort_t* __restrict__ attnb) {
  const int t = threadIdx.x;
  const size_t row = (size_t)blockIdx.x * 4 + (t >> 6);
  const int lane = t & 63;
  const size_t base = row * 1024 + lane * 16;
  ushort8 v0 = *reinterpret_cast<const ushort8*>(simsb + base);
  ushort8 v1 = *reinterpret_cast<const ushort8*>(simsb + base + 8);
  float xs[16];
  float mx = -INFINITY;
#pragma unroll
  for (int i = 0; i < 8; ++i) { xs[i] = bf2f(v0[i]); xs[i + 8] = bf2f(v1[i]); }
#pragma unroll
  for (int i = 0; i < 16; ++i) mx = fmaxf(mx, xs[i]);
#pragma unroll
  for (int off = 1; off < 64; off <<= 1) mx = fmaxf(mx, __shfl_xor(mx, off));
  float sum = 0.f;
#pragma unroll
  for (int i = 0; i < 16; ++i) { xs[i] = __expf(xs[i] - mx); sum += xs[i]; }
#pragma unroll
  for (int off = 1; off < 64; off <<= 1) sum += __shfl_xor(sum, off);
  const float inv = 1.f / sum;
  ushort8 o0, o1;
#pragma unroll
  for (int i = 0; i < 16; ++i) xs[i] *= inv;
#pragma unroll
  for (int i = 0; i < 4; ++i) {
    float4 f = make_float4(xs[4 * i], xs[4 * i + 1], xs[4 * i + 2], xs[4 * i + 3]);
    *reinterpret_cast<float4*>(attn + base + 4 * i) = f;
  }
#pragma unroll
  for (int i = 0; i < 8; ++i) { o0[i] = f2bf(xs[i]); o1[i] = f2bf(xs[i + 8]); }
  *reinterpret_cast<ushort8*>(attnb + base) = o0;
  *reinterpret_cast<ushort8*>(attnb + base + 8) = o1;
}

__global__ void pe_kernel(float* __restrict__ pe) {
  const int s = blockIdx.x, i = threadIdx.x;
  double div = exp((double)(2 * i) * (-log(10000.0) / 512.0));
  double a = (double)s * div;
  pe[s * 512 + 2 * i] = (float)sin(a);
  pe[s * 512 + 2 * i + 1] = (float)cos(a);
}

// All weight conversions + fc2 zero-padded to 128 rows.
__global__ __launch_bounds__(256) void cvt_all(
    const float* __restrict__ qkvw, const float* __restrict__ outw,
    const float* __restrict__ ff1w, const float* __restrict__ ff2w,
    const float* __restrict__ memw, const float* __restrict__ fc1w,
    const float* __restrict__ gc1w, const float* __restrict__ gc2w,
    const float* __restrict__ fc2w,
    ushort_t* qkvb, ushort_t* outb, ushort_t* ff1b, ushort_t* ff2b,
    ushort_t* memb, ushort_t* fc1b, ushort_t* gc1b, ushort_t* gc2b,
    ushort_t* fc2p) {
  const int gidx = blockIdx.x * 256 + threadIdx.x;  // < 2768896
  if (gidx >= 2768896) return;
  if (gidx >= 2752512) {
    const int off = gidx - 2752512;
    ushort4 o = {0, 0, 0, 0};
    if (off < 8192) {
      float4 v = reinterpret_cast<const float4*>(fc2w)[off];
      o.x = f2bf(v.x); o.y = f2bf(v.y); o.z = f2bf(v.z); o.w = f2bf(v.w);
    }
    reinterpret_cast<ushort4*>(fc2p)[off] = o;
    return;
  }
  const float* s; ushort_t* d; int off;
  if (gidx < 589824)        { s = qkvw; d = qkvb; off = gidx; }
  else if (gidx < 786432)   { s = outw; d = outb; off = gidx - 589824; }
  else if (gidx < 1572864)  { s = ff1w; d = ff1b; off = gidx - 786432; }
  else if (gidx < 2359296)  { s = ff2w; d = ff2b; off = gidx - 1572864; }
  else if (gidx < 2490368)  { s = memw; d = memb; off = gidx - 2359296; }
  else if (gidx < 2621440)  { s = fc1w; d = fc1b; off = gidx - 2490368; }
  else if (gidx < 2686976)  { s = gc1w; d = gc1b; off = gidx - 2621440; }
  else                      { s = gc2w; d = gc2b; off = gidx - 2686976; }
  float4 v = reinterpret_cast<const float4*>(s)[off];
  ushort4 o;
  o.x = f2bf(v.x); o.y = f2bf(v.y); o.z = f2bf(v.z); o.w = f2bf(v.w);
  reinterpret_cast<ushort4*>(d)[off] = o;
}

__global__ __launch_bounds__(256) void transpose_cvt(const float* __restrict__ in,
                                                     ushort_t* __restrict__ out) {
  const int g = blockIdx.x * 256 + threadIdx.x;
  const int r = g >> 9, c = g & 511;
  out[(size_t)c * 1024 + r] = f2bf(in[g]);
}

__global__ __launch_bounds__(256) void transpose_x_bf16(const float* __restrict__ x,
                                                        ushort_t* __restrict__ xtb) {
  __shared__ float Ls[64][65];
  const int sc = blockIdx.x, b = blockIdx.y;
  const int t = threadIdx.x;
  const int f = t & 63, sr = t >> 6;
#pragma unroll
  for (int j = 0; j < 16; ++j) {
    const int s = sr + 4 * j;
    Ls[s][f] = x[((size_t)(b * 512 + sc * 64 + s)) * 64 + f];
  }
  __syncthreads();
#pragma unroll
  for (int j = 0; j < 16; ++j) {
    const int fr = sr * 16 + j;
    xtb[((size_t)b * 64 + fr) * 512 + sc * 64 + f] = f2bf(Ls[f][fr]);
  }
}

// fmean + graph fused: one block per batch (256 threads).
__global__ __launch_bounds__(256) void fmean_graph(const float* __restrict__ x,
                                                   float* __restrict__ An) {
  __shared__ float part[4][64];
  __shared__ float fv[64];
  __shared__ float Am[64][65];
  const int b = blockIdx.x, t = threadIdx.x;
  const int f = t & 63, sg = t >> 6;
  const int i = t >> 2, g = t & 3;
  float acc = 0.f;
  const float* xp = x + ((size_t)b * 512 + sg) * 64 + f;
  for (int s = sg; s < 512; s += 4, xp += 256) acc += *xp;
  part[sg][f] = acc;
#pragma unroll
  for (int j = 0; j < 16; ++j) Am[i][g * 16 + j] = 0.f;
  __syncthreads();
  if (t < 64) {
    float m = (part[0][t] + part[1][t] + part[2][t] + part[3][t]) * (1.f / 512.f);
    float ss = m * m;
#pragma unroll
    for (int off = 32; off; off >>= 1) ss += __shfl_xor(ss, off);
    float n = fmaxf(sqrtf(ss), 1e-12f);
    fv[t] = m / n;
  }
  __syncthreads();
  const float fi = fv[i];
  unsigned int mask = 0;
  int sel[4];
  for (int r = 0; r < 4; ++r) {
    float best = -INFINITY;
    int bi = 1 << 30;
    for (int j = 0; j < 16; ++j) {
      if (mask & (1u << j)) continue;
      float v = fi * fv[g * 16 + j];
      if (v > best) { best = v; bi = g * 16 + j; }
    }
#pragma unroll
    for (int off = 1; off < 4; off <<= 1) {
      float ov = __shfl_xor(best, off);
      int oi = __shfl_xor(bi, off);
      if (ov > best || (ov == best && oi < bi)) { best = ov; bi = oi; }
    }
    sel[r] = bi;
    if ((bi >> 4) == g) mask |= 1u << (bi & 15);
  }
  if (g == 0) { Am[i][sel[1]] = 1.f; Am[i][sel[2]] = 1.f; Am[i][sel[3]] = 1.f; }
  __syncthreads();
  float vals[16];
  float deg = 0.f;
#pragma unroll
  for (int j0 = 0; j0 < 16; ++j0) {
    const int j = g * 16 + j0;
    float v = (j == i) ? 1.f : fmaxf(Am[i][j], Am[j][i]);
    vals[j0] = v;
    deg += v;
  }
#pragma unroll
  for (int off = 1; off < 4; off <<= 1) deg += __shfl_xor(deg, off);
  const float inv = 1.f / deg;
  float* out = An + ((size_t)b * 64 + i) * 64 + g * 16;
#pragma unroll
  for (int j0 = 0; j0 < 16; ++j0) out[j0] = vals[j0] * inv;
}

template <bool RELU, bool STORE_T>
__global__ __launch_bounds__(256) void bmm_an(const float* __restrict__ An,
                                              const float* __restrict__ X,
                                              float* __restrict__ Y,
                                              ushort_t* __restrict__ Yb) {
  __shared__ float Ag[64][68];
  __shared__ float Xs[64][68];
  const int nc = blockIdx.x << 6;
  const int b = blockIdx.y;
  const int t = threadIdx.x;
  {
    const int i = t >> 2, g0 = (t & 3) << 4;
    const float* ap = An + ((size_t)b * 64 + i) * 64 + g0;
#pragma unroll
    for (int j = 0; j < 16; ++j) Ag[g0 + j][i] = ap[j];
  }
  {
    const int g = t >> 2, n4 = (t & 3) << 4;
    const float* xp = X + ((size_t)b * 64 + g) * 512 + nc + n4;
#pragma unroll
    for (int j = 0; j < 4; ++j)
      *reinterpret_cast<float4*>(&Xs[g][n4 + 4 * j]) =
          *reinterpret_cast<const float4*>(xp + 4 * j);
  }
  __syncthreads();
  const int r0 = (t >> 4) << 2, c0 = (t & 15) << 2;
  float acc[4][4] = {{0.f, 0.f, 0.f, 0.f}, {0.f, 0.f, 0.f, 0.f},
                     {0.f, 0.f, 0.f, 0.f}, {0.f, 0.f, 0.f, 0.f}};
#pragma unroll 8
  for (int g = 0; g < 64; ++g) {
    float4 a4 = *reinterpret_cast<const float4*>(&Ag[g][r0]);
    float4 x4 = *reinterpret_cast<const float4*>(&Xs[g][c0]);
    OUTER16(acc, a4, x4);
  }
  if (!STORE_T) {
#pragma unroll
    for (int i = 0; i < 4; ++i) {
      float4 o = make_float4(acc[i][0], acc[i][1], acc[i][2], acc[i][3]);
      if (RELU) {
        o.x = fmaxf(o.x, 0.f); o.y = fmaxf(o.y, 0.f);
        o.z = fmaxf(o.z, 0.f); o.w = fmaxf(o.w, 0.f);
      }
      ushort4 ob;
      ob.x = f2bf(o.x); ob.y = f2bf(o.y); ob.z = f2bf(o.z); ob.w = f2bf(o.w);
      *reinterpret_cast<ushort4*>(Yb + ((size_t)b * 64 + r0 + i) * 512 + nc + c0) = ob;
    }
  } else {
#pragma unroll
    for (int j = 0; j < 4; ++j) {
      float4 o = make_float4(acc[0][j], acc[1][j], acc[2][j], acc[3][j]);
      *reinterpret_cast<float4*>(Y + ((size_t)b * 512 + nc + c0 + j) * 64 + r0) = o;
    }
  }
}

}  // namespace

extern "C" void kernel_launch(void* const* d_in, const int* in_sizes, int n_in,
                              void* d_out, int out_size, void* d_ws, size_t ws_size,
                              hipStream_t stream) {
  const float* x     = (const float*)d_in[0];
  const float* W_in  = (const float*)d_in[1];
  const float* b_in  = (const float*)d_in[2];
  const float* qkv_w = (const float*)d_in[3];
  const float* qkv_b = (const float*)d_in[4];
  const float* out_w = (const float*)d_in[5];
  const float* out_b = (const float*)d_in[6];
  const float* ln1_g = (const float*)d_in[7];
  const float* ln1_b = (const float*)d_in[8];
  const float* ln2_g = (const float*)d_in[9];
  const float* ln2_b = (const float*)d_in[10];
  const float* ff1_w = (const float*)d_in[11];
  const float* ff1_b = (const float*)d_in[12];
  const float* ff2_w = (const float*)d_in[13];
  const float* ff2_b = (const float*)d_in[14];
  const float* memw  = (const float*)d_in[15];
  const float* fc1_w = (const float*)d_in[16];
  const float* fc1_b = (const float*)d_in[17];
  const float* fc2_w = (const float*)d_in[18];
  const float* fc2_b = (const float*)d_in[19];
  const float* gc1_w = (const float*)d_in[20];
  const float* gc1_b = (const float*)d_in[21];
  const float* gc2_w = (const float*)d_in[22];
  const float* gc2_b = (const float*)d_in[23];

  char* wsb = (char*)d_ws;
  ushort_t* hb     = (ushort_t*)(wsb + 0);            // 16MB
  ushort_t* ctxb   = (ushort_t*)(wsb + 16 * MB);      // 16MB
  ushort_t* resb   = (ushort_t*)(wsb + 32 * MB);      // 16MB
  char*     U1     = wsb + 48 * MB;                   // 96MB shared region
  float*    pe     = (float*)(wsb + 144 * MB);        // 1MB
  ushort_t* qkv_wb = (ushort_t*)(wsb + 146 * MB);     // 4.5MB
  ushort_t* out_wb = (ushort_t*)(wsb + 151 * MB);     // 1.5MB
  ushort_t* ff1_wb = (ushort_t*)(wsb + 153 * MB);     // 6MB
  ushort_t* ff2_wb = (ushort_t*)(wsb + 160 * MB);     // 6MB
  ushort_t* mem_b  = (ushort_t*)(wsb + 166 * MB);     // 1MB
  ushort_t* memT_b = (ushort_t*)(wsb + 167 * MB);     // 1MB
  ushort_t* fc1_wb = (ushort_t*)(wsb + 168 * MB);     // 1MB
  ushort_t* gc1_wb = (ushort_t*)(wsb + 169 * MB);     // 0.5MB
  ushort_t* gc2_wb = (ushort_t*)(wsb + 169 * MB + 524288);  // 0.5MB
  ushort_t* fc2_wp = (ushort_t*)(wsb + 170 * MB);     // 128KB (128x512 padded)
  float*    An     = (float*)(wsb + 172 * MB);        // 512KB

  // U1 overlays (sequentially dead):
  ushort_t* qkvb    = (ushort_t*)U1;                  // 48MB per-layer qkv
  ushort_t* midb    = (ushort_t*)U1;                  // 64MB ff1 out
  ushort_t* catb    = (ushort_t*)U1;                  // 32MB [h|upd] (layer-3 on)
  ushort_t* simsb   = (ushort_t*)(U1 + 32 * MB);      // 32MB sims bf16
  ushort_t* attnb   = (ushort_t*)(U1 + 64 * MB);      // 32MB softmax bf16
  ushort_t* fc1outb = (ushort_t*)(U1 + 64 * MB);      // 16MB (after upd; attnb dead)
  // GCN scratch (after fc2):
  ushort_t* xtb  = (ushort_t*)U1;                      // 2MB
  float*    t1   = (float*)(U1 + 2 * MB);              // 4MB
  ushort_t* h1b  = (ushort_t*)(U1 + 6 * MB);           // 2MB
  float*    t2   = (float*)(U1 + 8 * MB);              // 4MB

  float* t_out = (float*)d_out;
  float* g_out = t_out + 1048576;
  float* attn  = g_out + 1048576;

  // ---- conversions / tables
  hipLaunchKernelGGL(cvt_all, dim3(10816), dim3(256), 0, stream,
                     qkv_w, out_w, ff1_w, ff2_w, memw, fc1_w, gc1_w, gc2_w, fc2_w,
                     qkv_wb, out_wb, ff1_wb, ff2_wb, mem_b, fc1_wb, gc1_wb, gc2_wb,
                     fc2_wp);
  hipLaunchKernelGGL(transpose_cvt, dim3(2048), dim3(256), 0, stream, memw, memT_b);
  hipLaunchKernelGGL(pe_kernel, dim3(512), dim3(256), 0, stream, pe);

  // ---- input projection + PE (bf16 out)
  hipLaunchKernelGGL(win_pe_gemm, dim3(256, 8), dim3(256), 0, stream,
                     x, W_in, b_in, pe, hb);

  for (int l = 0; l < 3; ++l) {
    hipLaunchKernelGGL((gemm256<false, true>), dim3(64, 6), dim3(512), 0, stream,
                       hb, qkv_wb + (size_t)l * 786432, qkv_b + l * 1536, qkvb,
                       512, 512, 1536);
    hipLaunchKernelGGL(flash_attn_mfma, dim3(8, 8, 32), dim3(256), 0, stream, qkvb, ctxb);
    hipLaunchKernelGGL((gemm_bf16<false, true>), dim3(128, 4), dim3(256), 0, stream,
                       ctxb, out_wb + (size_t)l * 262144, out_b + l * 512, resb,
                       512, 512, 512, 512);
    hipLaunchKernelGGL(ln_wave, dim3(Mrows / 4), dim3(256), 0, stream,
                       hb, resb, ln1_g + l * 512, ln1_b + l * 512, hb, 512);
    hipLaunchKernelGGL((gemm256<true, true>), dim3(64, 8), dim3(512), 0, stream,
                       hb, ff1_wb + (size_t)l * 1048576, ff1_b + l * 2048, midb,
                       512, 512, 2048);
    hipLaunchKernelGGL((gemm_bf16<false, true>), dim3(128, 4), dim3(256), 0, stream,
                       midb, ff2_wb + (size_t)l * 1048576, ff2_b + l * 512, resb,
                       2048, 2048, 512, 512);
    if (l < 2) {
      hipLaunchKernelGGL(ln_wave, dim3(Mrows / 4), dim3(256), 0, stream,
                         hb, resb, ln2_g + l * 512, ln2_b + l * 512, hb, 512);
    } else {
      hipLaunchKernelGGL(ln_wave, dim3(Mrows / 4), dim3(256), 0, stream,
                         hb, resb, ln2_g + l * 512, ln2_b + l * 512, catb, 1024);
    }
  }

  // ---- memory attention head
  hipLaunchKernelGGL((gemm256<false, true>), dim3(64, 4), dim3(512), 0, stream,
                     catb, mem_b, (const float*)nullptr, simsb,
                     512, 1024, 1024);
  hipLaunchKernelGGL(softmax_wave, dim3(Mrows / 4), dim3(256), 0, stream,
                     simsb, attn, attnb);
  hipLaunchKernelGGL((gemm_bf16<false, true>), dim3(128, 4), dim3(256), 0, stream,
                     attnb, memT_b, (const float*)nullptr, catb + 512,
                     1024, 1024, 1024, 512);
  hipLaunchKernelGGL((gemm_bf16<true, true>), dim3(128, 4), dim3(256), 0, stream,
                     catb, fc1_wb, fc1_b, fc1outb, 1024, 1024, 512, 512);
  hipLaunchKernelGGL((gemm_bf16<false, false>), dim3(128, 1), dim3(256), 0, stream,
                     fc1outb, fc2_wp, fc2_b, t_out, 512, 512, 64, 64);

  // ---- GCN branch
  hipLaunchKernelGGL(fmean_graph, dim3(32), dim3(256), 0, stream, x, An);
  hipLaunchKernelGGL(transpose_x_bf16, dim3(8, 32), dim3(256), 0, stream, x, xtb);
  hipLaunchKernelGGL((gemm_bf16<false, false>), dim3(16, 4), dim3(256), 0, stream,
                     xtb, gc1_wb, gc1_b, t1, 512, 512, 512, 512);
  hipLaunchKernelGGL((bmm_an<true, false>), dim3(8, 32), dim3(256), 0, stream,
                     An, t1, (float*)nullptr, h1b);
  hipLaunchKernelGGL((gemm_bf16<false, false>), dim3(16, 4), dim3(256), 0, stream,
                     h1b, gc2_wb, gc2_b, t2, 512, 512, 512, 512);
  hipLaunchKernelGGL((bmm_an<false, true>), dim3(8, 32), dim3(256), 0, stream,
                     An, t2, g_out, (ushort_t*)nullptr);
}